// Round 1
// baseline (4609.704 us; speedup 1.0000x reference)
//
#include <hip/hip_runtime.h>
#include <hip/hip_bf16.h>
#include <math.h>

#define NUM_HEADS 12
#define HEAD_DIM 128
#define DIM 1536
#define SINK_SIZE 1
#define MAX_ATT 1000000
#define EPS 1e-6f
#define SCALE 0.08838834764831845f  // 1/sqrt(128)

// ---------------- GEMM: C[M][N] = A[M][K] @ W[N][K]^T + bias[N] ----------------
__global__ __launch_bounds__(256) void gemm_nt(const float* __restrict__ A,
                                               const float* __restrict__ W,
                                               const float* __restrict__ bias,
                                               float* __restrict__ C,
                                               int M, int N, int K) {
    __shared__ float As[16][65];   // [k][m], padded to kill write conflicts
    __shared__ float Bs[16][65];   // [k][n]
    const int tx = threadIdx.x, ty = threadIdx.y;   // 16x16
    const int t  = ty * 16 + tx;
    const int m0 = blockIdx.y * 64, n0 = blockIdx.x * 64;

    float acc[4][4] = {};
    const int lr = t >> 2;          // 0..63 tile row
    const int lc = (t & 3) * 4;     // 0,4,8,12 k-offset

    for (int k0 = 0; k0 < K; k0 += 16) {
        float4 av = make_float4(0.f, 0.f, 0.f, 0.f);
        float4 bv = make_float4(0.f, 0.f, 0.f, 0.f);
        int m = m0 + lr;
        int n = n0 + lr;
        if (m < M) av = *(const float4*)&A[(size_t)m * K + k0 + lc];
        if (n < N) bv = *(const float4*)&W[(size_t)n * K + k0 + lc];
        As[lc + 0][lr] = av.x; As[lc + 1][lr] = av.y;
        As[lc + 2][lr] = av.z; As[lc + 3][lr] = av.w;
        Bs[lc + 0][lr] = bv.x; Bs[lc + 1][lr] = bv.y;
        Bs[lc + 2][lr] = bv.z; Bs[lc + 3][lr] = bv.w;
        __syncthreads();

        #pragma unroll
        for (int kk = 0; kk < 16; ++kk) {
            float a[4], b[4];
            #pragma unroll
            for (int i = 0; i < 4; ++i) a[i] = As[kk][ty + 16 * i];
            #pragma unroll
            for (int j = 0; j < 4; ++j) b[j] = Bs[kk][tx + 16 * j];
            #pragma unroll
            for (int i = 0; i < 4; ++i)
                #pragma unroll
                for (int j = 0; j < 4; ++j) acc[i][j] += a[i] * b[j];
        }
        __syncthreads();
    }

    #pragma unroll
    for (int i = 0; i < 4; ++i) {
        int m = m0 + ty + 16 * i;
        if (m >= M) continue;
        #pragma unroll
        for (int j = 0; j < 4; ++j) {
            int n = n0 + tx + 16 * j;
            if (n < N) C[(size_t)m * N + n] = acc[i][j] + bias[n];
        }
    }
}

// ------------- RMSNorm + RoPE, in place, one block per (token, q|k) -------------
__global__ __launch_bounds__(256) void norm_rope(float* __restrict__ qbuf,
                                                 float* __restrict__ kbuf,
                                                 const float* __restrict__ gq,
                                                 const float* __restrict__ gk,
                                                 const float* __restrict__ fcos,
                                                 const float* __restrict__ fsin,
                                                 const int* __restrict__ gh,
                                                 const int* __restrict__ gw,
                                                 const int* __restrict__ cs) {
    const int s = blockIdx.x;
    float* buf = blockIdx.y ? kbuf : qbuf;
    const float* g = blockIdx.y ? gk : gq;
    __shared__ float row[DIM];
    __shared__ float red[4];
    const int t = threadIdx.x;
    float* p = buf + (size_t)s * DIM;

    float vals[6];
    float ss = 0.f;
    #pragma unroll
    for (int i = 0; i < 6; ++i) {
        vals[i] = p[t + 256 * i];
        ss += vals[i] * vals[i];
    }
    #pragma unroll
    for (int off = 32; off > 0; off >>= 1) ss += __shfl_down(ss, off, 64);
    if ((t & 63) == 0) red[t >> 6] = ss;
    __syncthreads();
    float tot = red[0] + red[1] + red[2] + red[3];
    float rr = rsqrtf(tot / (float)DIM + EPS);
    #pragma unroll
    for (int i = 0; i < 6; ++i) row[t + 256 * i] = vals[i] * rr * g[t + 256 * i];
    __syncthreads();

    const int fs = gh[0] * gw[0];          // 780
    const int sf = cs[0] / fs;             // start_frame = 11
    const int fi = s / fs;
    const int rem = s - fi * fs;
    const int hi = rem / gw[0];
    const int wi = rem - hi * gw[0];

    #pragma unroll
    for (int r = 0; r < 3; ++r) {
        int pi = t + 256 * r;              // pair index 0..767
        int h = pi >> 6, j = pi & 63;
        int trow = (j < 22) ? (sf + fi) : ((j < 43) ? hi : wi);
        float c = fcos[trow * 64 + j];
        float sn = fsin[trow * 64 + j];
        float re = row[h * 128 + 2 * j];
        float im = row[h * 128 + 2 * j + 1];
        p[h * 128 + 2 * j]     = re * c - im * sn;
        p[h * 128 + 2 * j + 1] = re * sn + im * c;
    }
}

// -------------------------- flash-style fp32 attention --------------------------
#define TQ 16
#define TK 32
__global__ __launch_bounds__(256) void attn(const float* __restrict__ qbuf,
                                            const float* __restrict__ knew,
                                            const float* __restrict__ vnew,
                                            const float* __restrict__ cache_k,
                                            const float* __restrict__ cache_v,
                                            float* __restrict__ obuf,
                                            int S, int cache_len,
                                            const int* __restrict__ gh,
                                            const int* __restrict__ gw,
                                            const int* __restrict__ cs,
                                            const int* __restrict__ ge,
                                            const int* __restrict__ le) {
    // cache roll/append index math (reference semantics, no actual cache writes)
    const int fs = gh[0] * gw[0];
    const int sink = SINK_SIZE * fs;
    const int current_end = cs[0] + S;
    int lei, nev = 0;
    bool rolled = false;
    if (current_end > ge[0] && S + le[0] > cache_len) {
        nev = S + le[0] - cache_len;
        lei = le[0] + current_end - ge[0] - nev;
        rolled = true;
    } else {
        lei = le[0] + current_end - ge[0];
    }
    const int lsi = lei - S;
    const int kstart = max(0, lei - MAX_ATT);
    const int nkeys = lei - kstart;

    const int head = blockIdx.y;
    const int q0 = blockIdx.x * TQ;
    const int t = threadIdx.x;

    __shared__ __align__(16) float Qs[TQ][132];
    __shared__ __align__(16) float Ks[TK][132];
    __shared__ __align__(16) float Vs[TK][132];
    __shared__ float Ss[TQ][33];
    __shared__ float rowm[TQ], rowl[TQ], rowf[TQ];

    // stage Q tile (zero-pad OOB rows)
    #pragma unroll
    for (int r = 0; r < 2; ++r) {
        int idx = t * 2 + r;               // 0..511
        int row = idx >> 5, c4 = idx & 31;
        float4 qv = make_float4(0.f, 0.f, 0.f, 0.f);
        if (q0 + row < S)
            qv = *(const float4*)&qbuf[(size_t)(q0 + row) * DIM + head * HEAD_DIM + c4 * 4];
        *(float4*)&Qs[row][c4 * 4] = qv;
    }
    if (t < TQ) { rowm[t] = -INFINITY; rowl[t] = 0.f; }
    float o[8] = {};

    for (int j0 = 0; j0 < nkeys; j0 += TK) {
        // stage K/V tile with source remap; zero-fill invalid rows
        #pragma unroll
        for (int r = 0; r < 4; ++r) {
            int idx = t + 256 * r;          // 0..1023
            int row = idx >> 5, c4 = idx & 31;
            float4 kv = make_float4(0.f, 0.f, 0.f, 0.f);
            float4 vv = kv;
            int j = j0 + row;
            if (j < nkeys) {
                int a = kstart + j;
                const float *kp, *vp;
                if (a >= lsi) {
                    kp = knew + (size_t)(a - lsi) * DIM;
                    vp = vnew + (size_t)(a - lsi) * DIM;
                } else {
                    int src = (rolled && a >= sink) ? a + nev : a;
                    kp = cache_k + (size_t)src * DIM;
                    vp = cache_v + (size_t)src * DIM;
                }
                kv = *(const float4*)(kp + head * HEAD_DIM + c4 * 4);
                vv = *(const float4*)(vp + head * HEAD_DIM + c4 * 4);
            }
            *(float4*)&Ks[row][c4 * 4] = kv;
            *(float4*)&Vs[row][c4 * 4] = vv;
        }
        __syncthreads();

        // scores: thread -> (qi = t&15, ki = t>>4 and ki+16)
        {
            int qi = t & 15, ki = t >> 4;
            const float4* qr = (const float4*)&Qs[qi][0];
            const float4* k0r = (const float4*)&Ks[ki][0];
            const float4* k1r = (const float4*)&Ks[ki + 16][0];
            float d0 = 0.f, d1 = 0.f;
            #pragma unroll 8
            for (int c = 0; c < 32; ++c) {
                float4 q4 = qr[c], a4 = k0r[c], b4 = k1r[c];
                d0 += q4.x * a4.x + q4.y * a4.y + q4.z * a4.z + q4.w * a4.w;
                d1 += q4.x * b4.x + q4.y * b4.y + q4.z * b4.z + q4.w * b4.w;
            }
            d0 *= SCALE; d1 *= SCALE;
            if (j0 + ki >= nkeys) d0 = -INFINITY;
            if (j0 + ki + 16 >= nkeys) d1 = -INFINITY;
            Ss[qi][ki] = d0;
            Ss[qi][ki + 16] = d1;
        }
        __syncthreads();

        // online softmax: 16 lanes per row
        {
            int rq = t >> 4, u = t & 15;
            float s0 = Ss[rq][u], s1 = Ss[rq][u + 16];
            float mt = fmaxf(s0, s1);
            #pragma unroll
            for (int off = 1; off < 16; off <<= 1) mt = fmaxf(mt, __shfl_xor(mt, off, 16));
            float mold = rowm[rq];
            float mnew = fmaxf(mold, mt);
            float p0 = __expf(s0 - mnew);
            float p1 = __expf(s1 - mnew);
            float ls = p0 + p1;
            #pragma unroll
            for (int off = 1; off < 16; off <<= 1) ls += __shfl_xor(ls, off, 16);
            Ss[rq][u] = p0;
            Ss[rq][u + 16] = p1;
            if (u == 0) {
                float f = __expf(mold - mnew);
                rowf[rq] = f;
                rowl[rq] = rowl[rq] * f + ls;
                rowm[rq] = mnew;
            }
        }
        __syncthreads();

        // PV: thread -> (qi = t>>4, 8 dims at dg*8)
        {
            int qo = t >> 4, dg = t & 15;
            float f = rowf[qo];
            #pragma unroll
            for (int j = 0; j < 8; ++j) o[j] *= f;
            #pragma unroll 4
            for (int kk = 0; kk < TK; ++kk) {
                float pp = Ss[qo][kk];
                float4 v0 = *(const float4*)&Vs[kk][dg * 8];
                float4 v1 = *(const float4*)&Vs[kk][dg * 8 + 4];
                o[0] += pp * v0.x; o[1] += pp * v0.y; o[2] += pp * v0.z; o[3] += pp * v0.w;
                o[4] += pp * v1.x; o[5] += pp * v1.y; o[6] += pp * v1.z; o[7] += pp * v1.w;
            }
        }
        __syncthreads();
    }

    // epilogue
    {
        int qo = t >> 4, dg = t & 15;
        if (q0 + qo < S) {
            float inv = 1.f / rowl[qo];
            float4 r0 = make_float4(o[0] * inv, o[1] * inv, o[2] * inv, o[3] * inv);
            float4 r1 = make_float4(o[4] * inv, o[5] * inv, o[6] * inv, o[7] * inv);
            float* dst = &obuf[(size_t)(q0 + qo) * DIM + head * HEAD_DIM + dg * 8];
            *(float4*)dst = r0;
            *(float4*)(dst + 4) = r1;
        }
    }
}

// ----------------------------------- launch -----------------------------------
extern "C" void kernel_launch(void* const* d_in, const int* in_sizes, int n_in,
                              void* d_out, int out_size, void* d_ws, size_t ws_size,
                              hipStream_t stream) {
    const float* x       = (const float*)d_in[0];
    const float* fcos    = (const float*)d_in[1];
    const float* fsin    = (const float*)d_in[2];
    const float* cache_k = (const float*)d_in[3];
    const float* cache_v = (const float*)d_in[4];
    const float* Wq      = (const float*)d_in[5];
    const float* bq      = (const float*)d_in[6];
    const float* Wk      = (const float*)d_in[7];
    const float* bk      = (const float*)d_in[8];
    const float* Wv      = (const float*)d_in[9];
    const float* bv      = (const float*)d_in[10];
    const float* Wo      = (const float*)d_in[11];
    const float* bo      = (const float*)d_in[12];
    const float* gq      = (const float*)d_in[13];
    const float* gk      = (const float*)d_in[14];
    const int* gh        = (const int*)d_in[16];
    const int* gw        = (const int*)d_in[17];
    const int* cs        = (const int*)d_in[18];
    const int* ge        = (const int*)d_in[19];
    const int* le        = (const int*)d_in[20];

    const int S = in_sizes[0] / DIM;           // 1560
    const int cache_len = in_sizes[3] / DIM;   // 9360

    float* q   = (float*)d_ws;
    float* k   = q + (size_t)S * DIM;
    float* v   = k + (size_t)S * DIM;
    float* att = v + (size_t)S * DIM;
    float* out = (float*)d_out;

    dim3 gb(16, 16);
    dim3 gg((DIM + 63) / 64, (S + 63) / 64);

    gemm_nt<<<gg, gb, 0, stream>>>(x, Wq, bq, q, S, DIM, DIM);
    gemm_nt<<<gg, gb, 0, stream>>>(x, Wk, bk, k, S, DIM, DIM);
    gemm_nt<<<gg, gb, 0, stream>>>(x, Wv, bv, v, S, DIM, DIM);

    norm_rope<<<dim3(S, 2), 256, 0, stream>>>(q, k, gq, gk, fcos, fsin, gh, gw, cs);

    attn<<<dim3((S + TQ - 1) / TQ, NUM_HEADS), 256, 0, stream>>>(
        q, k, v, cache_k, cache_v, att, S, cache_len, gh, gw, cs, ge, le);

    gemm_nt<<<gg, gb, 0, stream>>>(att, Wo, bo, out, S, DIM, DIM);
}

// Round 5
// 1664.876 us; speedup vs baseline: 2.7688x; 2.7688x over previous
//
#include <hip/hip_runtime.h>
#include <hip/hip_bf16.h>
#include <math.h>

#define NUM_HEADS 12
#define HEAD_DIM 128
#define DIM 1536
#define SINK_SIZE 1
#define MAX_ATT 1000000
#define EPS 1e-6f
#define SCALE 0.08838834764831845f  // 1/sqrt(128)

typedef __attribute__((ext_vector_type(8))) short short8;
typedef __attribute__((ext_vector_type(4))) float f32x4;

static __device__ __forceinline__ unsigned short f2b(float f) {
    __hip_bfloat16 h = __float2bfloat16(f);
    return __builtin_bit_cast(unsigned short, h);
}
static __device__ __forceinline__ float b2f(unsigned short u) {
    unsigned int v = ((unsigned int)u) << 16;
    return __builtin_bit_cast(float, v);
}

// ---------------- GEMM: C[M][N] = A[M][K] @ W[N][K]^T + bias[N] ----------------
__global__ __launch_bounds__(256) void gemm_nt(const float* __restrict__ A,
                                               const float* __restrict__ W,
                                               const float* __restrict__ bias,
                                               float* __restrict__ C,
                                               int M, int N, int K) {
    __shared__ float As[16][65];
    __shared__ float Bs[16][65];
    const int tx = threadIdx.x, ty = threadIdx.y;
    const int t  = ty * 16 + tx;
    const int m0 = blockIdx.y * 64, n0 = blockIdx.x * 64;

    float acc[4][4] = {};
    const int lr = t >> 2;
    const int lc = (t & 3) * 4;

    for (int k0 = 0; k0 < K; k0 += 16) {
        float4 av = make_float4(0.f, 0.f, 0.f, 0.f);
        float4 bv = make_float4(0.f, 0.f, 0.f, 0.f);
        int m = m0 + lr;
        int n = n0 + lr;
        if (m < M) av = *(const float4*)&A[(size_t)m * K + k0 + lc];
        if (n < N) bv = *(const float4*)&W[(size_t)n * K + k0 + lc];
        As[lc + 0][lr] = av.x; As[lc + 1][lr] = av.y;
        As[lc + 2][lr] = av.z; As[lc + 3][lr] = av.w;
        Bs[lc + 0][lr] = bv.x; Bs[lc + 1][lr] = bv.y;
        Bs[lc + 2][lr] = bv.z; Bs[lc + 3][lr] = bv.w;
        __syncthreads();

        #pragma unroll
        for (int kk = 0; kk < 16; ++kk) {
            float a[4], b[4];
            #pragma unroll
            for (int i = 0; i < 4; ++i) a[i] = As[kk][ty + 16 * i];
            #pragma unroll
            for (int j = 0; j < 4; ++j) b[j] = Bs[kk][tx + 16 * j];
            #pragma unroll
            for (int i = 0; i < 4; ++i)
                #pragma unroll
                for (int j = 0; j < 4; ++j) acc[i][j] += a[i] * b[j];
        }
        __syncthreads();
    }

    #pragma unroll
    for (int i = 0; i < 4; ++i) {
        int m = m0 + ty + 16 * i;
        if (m >= M) continue;
        #pragma unroll
        for (int j = 0; j < 4; ++j) {
            int n = n0 + tx + 16 * j;
            if (n < N) C[(size_t)m * N + n] = acc[i][j] + bias[n];
        }
    }
}

// ------------- RMSNorm + RoPE, in place, one block per (token, q|k) -------------
__global__ __launch_bounds__(256) void norm_rope(float* __restrict__ qbuf,
                                                 float* __restrict__ kbuf,
                                                 const float* __restrict__ gq,
                                                 const float* __restrict__ gk,
                                                 const float* __restrict__ fcos,
                                                 const float* __restrict__ fsin,
                                                 const int* __restrict__ gh,
                                                 const int* __restrict__ gw,
                                                 const int* __restrict__ cs) {
    const int s = blockIdx.x;
    float* buf = blockIdx.y ? kbuf : qbuf;
    const float* g = blockIdx.y ? gk : gq;
    __shared__ float row[DIM];
    __shared__ float red[4];
    const int t = threadIdx.x;
    float* p = buf + (size_t)s * DIM;

    float vals[6];
    float ss = 0.f;
    #pragma unroll
    for (int i = 0; i < 6; ++i) {
        vals[i] = p[t + 256 * i];
        ss += vals[i] * vals[i];
    }
    #pragma unroll
    for (int off = 32; off > 0; off >>= 1) ss += __shfl_down(ss, off, 64);
    if ((t & 63) == 0) red[t >> 6] = ss;
    __syncthreads();
    float tot = red[0] + red[1] + red[2] + red[3];
    float rr = rsqrtf(tot / (float)DIM + EPS);
    #pragma unroll
    for (int i = 0; i < 6; ++i) row[t + 256 * i] = vals[i] * rr * g[t + 256 * i];
    __syncthreads();

    const int fs = gh[0] * gw[0];
    const int sf = cs[0] / fs;
    const int fi = s / fs;
    const int rem = s - fi * fs;
    const int hi = rem / gw[0];
    const int wi = rem - hi * gw[0];

    #pragma unroll
    for (int r = 0; r < 3; ++r) {
        int pi = t + 256 * r;
        int h = pi >> 6, j = pi & 63;
        int trow = (j < 22) ? (sf + fi) : ((j < 43) ? hi : wi);
        float c = fcos[trow * 64 + j];
        float sn = fsin[trow * 64 + j];
        float re = row[h * 128 + 2 * j];
        float im = row[h * 128 + 2 * j + 1];
        p[h * 128 + 2 * j]     = re * c - im * sn;
        p[h * 128 + 2 * j + 1] = re * sn + im * c;
    }
}

// -------------------------- bf16 MFMA flash attention --------------------------
// Block: 256 threads = 4 waves; Q-tile 64 rows (16/wave); K-tile 64 keys.
// Fragment layouts (verified m89/m92): A/B frag = 8 contiguous k at row lane&15,
// k-window 8*(lane>>4); C/D: col=lane&15, row=4*(lane>>4)+reg.
__device__ __forceinline__ const float* key_src(const float* cache, const float* fresh,
                                                int a, int lsi, int sink, int nev,
                                                bool rolled) {
    if (a >= lsi) return fresh + (size_t)(a - lsi) * DIM;
    int srow = (rolled && a >= sink) ? a + nev : a;
    return cache + (size_t)srow * DIM;
}

__global__ __launch_bounds__(256) void attn_mfma(const float* __restrict__ qbuf,
                                                 const float* __restrict__ knew,
                                                 const float* __restrict__ vnew,
                                                 const float* __restrict__ cache_k,
                                                 const float* __restrict__ cache_v,
                                                 float* __restrict__ obuf,
                                                 int S, int cache_len,
                                                 const int* __restrict__ gh,
                                                 const int* __restrict__ gw,
                                                 const int* __restrict__ cs,
                                                 const int* __restrict__ ge,
                                                 const int* __restrict__ le) {
    // roll/append index math (no cache writes; read-side remap)
    const int fs = gh[0] * gw[0];
    const int sink = SINK_SIZE * fs;
    const int current_end = cs[0] + S;
    int lei, nev = 0;
    bool rolled = false;
    if (current_end > ge[0] && S + le[0] > cache_len) {
        nev = S + le[0] - cache_len;
        lei = le[0] + current_end - ge[0] - nev;
        rolled = true;
    } else {
        lei = le[0] + current_end - ge[0];
    }
    const int lsi = lei - S;
    const int kstart = max(0, lei - MAX_ATT);
    const int nkeys = lei - kstart;

    const int head = blockIdx.y;
    const int q0 = blockIdx.x * 64;
    const int tid = threadIdx.x;
    const int l = tid & 63, wv = tid >> 6;
    const int g = l >> 4, c = l & 15;

    // LDS: strides chosen so b128 fragment reads are 16B-aligned and <=2-way banked
    __shared__ __align__(16) unsigned short Ks[64][136];   // [key][d]
    __shared__ __align__(16) unsigned short Vt[128][72];   // [d][key]  (V transposed)
    __shared__ __align__(16) unsigned short Pl[4][16][72]; // [wave][q][key]

    // Q A-fragments in registers: row = c, k = ds*32 + 8g + j
    short8 qf[4];
    {
        int qrow = q0 + wv * 16 + c;
        const float* qp = qbuf + (size_t)qrow * DIM + head * HEAD_DIM + g * 8;
        #pragma unroll
        for (int ds = 0; ds < 4; ++ds) {
            short8 w = 0;
            if (qrow < S) {
                float4 a4 = *(const float4*)(qp + ds * 32);
                float4 b4 = *(const float4*)(qp + ds * 32 + 4);
                w[0] = (short)f2b(a4.x); w[1] = (short)f2b(a4.y);
                w[2] = (short)f2b(a4.z); w[3] = (short)f2b(a4.w);
                w[4] = (short)f2b(b4.x); w[5] = (short)f2b(b4.y);
                w[6] = (short)f2b(b4.z); w[7] = (short)f2b(b4.w);
            }
            qf[ds] = w;
        }
    }

    f32x4 accO[8];
    #pragma unroll
    for (int nb = 0; nb < 8; ++nb) accO[nb] = 0.f;
    float m_r[4], l_r[4];
    #pragma unroll
    for (int r = 0; r < 4; ++r) { m_r[r] = -INFINITY; l_r[r] = 0.f; }

    // staging thread mapping
    const int kkey = tid >> 2, kdq = tid & 3;   // K: 1 key row, 32 d per thread
    const int vkp = tid & 31, vdg = tid >> 5;   // V: 2 key rows, 16 d per thread

    for (int j0 = 0; j0 < nkeys; j0 += 64) {
        // ---- stage K tile: Ks[key][d] bf16 ----
        {
            int j = j0 + kkey;
            const float* src = nullptr;
            if (j < nkeys)
                src = key_src(cache_k, knew, kstart + j, lsi, sink, nev, rolled)
                      + head * HEAD_DIM + kdq * 32;
            #pragma unroll
            for (int s4 = 0; s4 < 4; ++s4) {
                short8 w = 0;
                if (src) {
                    float4 a4 = *(const float4*)(src + s4 * 8);
                    float4 b4 = *(const float4*)(src + s4 * 8 + 4);
                    w[0] = (short)f2b(a4.x); w[1] = (short)f2b(a4.y);
                    w[2] = (short)f2b(a4.z); w[3] = (short)f2b(a4.w);
                    w[4] = (short)f2b(b4.x); w[5] = (short)f2b(b4.y);
                    w[6] = (short)f2b(b4.z); w[7] = (short)f2b(b4.w);
                }
                *(short8*)&Ks[kkey][kdq * 32 + s4 * 8] = w;
            }
        }
        // ---- stage V tile transposed: Vt[d][key], packed pair writes ----
        {
            int ja = j0 + 2 * vkp, jb = ja + 1;
            const float* sa = nullptr;
            const float* sb = nullptr;
            if (ja < nkeys)
                sa = key_src(cache_v, vnew, kstart + ja, lsi, sink, nev, rolled)
                     + head * HEAD_DIM + vdg * 16;
            if (jb < nkeys)
                sb = key_src(cache_v, vnew, kstart + jb, lsi, sink, nev, rolled)
                     + head * HEAD_DIM + vdg * 16;
            float ra[16], rb[16];
            #pragma unroll
            for (int i = 0; i < 16; ++i) { ra[i] = 0.f; rb[i] = 0.f; }
            if (sa) {
                #pragma unroll
                for (int qq = 0; qq < 4; ++qq) {
                    float4 t4 = *(const float4*)(sa + qq * 4);
                    ra[qq * 4 + 0] = t4.x; ra[qq * 4 + 1] = t4.y;
                    ra[qq * 4 + 2] = t4.z; ra[qq * 4 + 3] = t4.w;
                }
            }
            if (sb) {
                #pragma unroll
                for (int qq = 0; qq < 4; ++qq) {
                    float4 t4 = *(const float4*)(sb + qq * 4);
                    rb[qq * 4 + 0] = t4.x; rb[qq * 4 + 1] = t4.y;
                    rb[qq * 4 + 2] = t4.z; rb[qq * 4 + 3] = t4.w;
                }
            }
            #pragma unroll
            for (int i = 0; i < 16; ++i) {
                unsigned int pk = (unsigned int)f2b(ra[i]) | ((unsigned int)f2b(rb[i]) << 16);
                *(unsigned int*)&Vt[vdg * 16 + i][2 * vkp] = pk;
            }
        }
        __syncthreads();

        // ---- QK^T: 16 MFMAs -> accS[kb] holds S[4g+r][16kb+c] ----
        f32x4 accS[4];
        #pragma unroll
        for (int kb = 0; kb < 4; ++kb) accS[kb] = 0.f;
        #pragma unroll
        for (int kb = 0; kb < 4; ++kb) {
            #pragma unroll
            for (int ds = 0; ds < 4; ++ds) {
                short8 kf = *(const short8*)&Ks[kb * 16 + c][ds * 32 + g * 8];
                accS[kb] = __builtin_amdgcn_mfma_f32_16x16x32_bf16(qf[ds], kf, accS[kb], 0, 0, 0);
            }
        }

        // ---- online softmax (row stats via 16-lane shuffle groups) ----
        bool maskk[4];
        #pragma unroll
        for (int kb = 0; kb < 4; ++kb) maskk[kb] = (j0 + kb * 16 + c) >= nkeys;

        #pragma unroll
        for (int r = 0; r < 4; ++r) {
            float sv[4];
            #pragma unroll
            for (int kb = 0; kb < 4; ++kb)
                sv[kb] = maskk[kb] ? -INFINITY : accS[kb][r] * SCALE;
            float mt = fmaxf(fmaxf(sv[0], sv[1]), fmaxf(sv[2], sv[3]));
            #pragma unroll
            for (int off = 1; off < 16; off <<= 1)
                mt = fmaxf(mt, __shfl_xor(mt, off, 64));
            float mn = fmaxf(m_r[r], mt);
            float fr = __expf(m_r[r] - mn);
            m_r[r] = mn;
            float ls = 0.f;
            #pragma unroll
            for (int kb = 0; kb < 4; ++kb) {
                float pv = __expf(sv[kb] - mn);
                unsigned short pb = f2b(pv);
                ls += b2f(pb);   // accumulate the bf16-rounded value (matches PV numerator)
                Pl[wv][4 * g + r][kb * 16 + c] = pb;
            }
            #pragma unroll
            for (int off = 1; off < 16; off <<= 1)
                ls += __shfl_xor(ls, off, 64);
            l_r[r] = l_r[r] * fr + ls;
            #pragma unroll
            for (int nb = 0; nb < 8; ++nb) accO[nb][r] *= fr;
        }

        // drain own-wave P writes before reading them as fragments
        asm volatile("s_waitcnt lgkmcnt(0)" ::: "memory");
        __builtin_amdgcn_sched_barrier(0);

        // ---- PV: 16 MFMAs -> accO[nb] holds O[4g+r][16nb+c] ----
        short8 pa0 = *(const short8*)&Pl[wv][c][g * 8];
        short8 pa1 = *(const short8*)&Pl[wv][c][32 + g * 8];
        #pragma unroll
        for (int nb = 0; nb < 8; ++nb) {
            short8 vb0 = *(const short8*)&Vt[nb * 16 + c][g * 8];
            short8 vb1 = *(const short8*)&Vt[nb * 16 + c][32 + g * 8];
            accO[nb] = __builtin_amdgcn_mfma_f32_16x16x32_bf16(pa0, vb0, accO[nb], 0, 0, 0);
            accO[nb] = __builtin_amdgcn_mfma_f32_16x16x32_bf16(pa1, vb1, accO[nb], 0, 0, 0);
        }
        __syncthreads();
    }

    // ---- epilogue ----
    #pragma unroll
    for (int r = 0; r < 4; ++r) {
        int row = q0 + wv * 16 + 4 * g + r;
        if (row >= S) continue;
        float inv = 1.f / l_r[r];
        #pragma unroll
        for (int nb = 0; nb < 8; ++nb)
            obuf[(size_t)row * DIM + head * HEAD_DIM + nb * 16 + c] = accO[nb][r] * inv;
    }
}

// ----------------------------------- launch -----------------------------------
extern "C" void kernel_launch(void* const* d_in, const int* in_sizes, int n_in,
                              void* d_out, int out_size, void* d_ws, size_t ws_size,
                              hipStream_t stream) {
    const float* x       = (const float*)d_in[0];
    const float* fcos    = (const float*)d_in[1];
    const float* fsin    = (const float*)d_in[2];
    const float* cache_k = (const float*)d_in[3];
    const float* cache_v = (const float*)d_in[4];
    const float* Wq      = (const float*)d_in[5];
    const float* bq      = (const float*)d_in[6];
    const float* Wk      = (const float*)d_in[7];
    const float* bk      = (const float*)d_in[8];
    const float* Wv      = (const float*)d_in[9];
    const float* bv      = (const float*)d_in[10];
    const float* Wo      = (const float*)d_in[11];
    const float* bo      = (const float*)d_in[12];
    const float* gq      = (const float*)d_in[13];
    const float* gk      = (const float*)d_in[14];
    const int* gh        = (const int*)d_in[16];
    const int* gw        = (const int*)d_in[17];
    const int* cs        = (const int*)d_in[18];
    const int* ge        = (const int*)d_in[19];
    const int* le        = (const int*)d_in[20];

    const int S = in_sizes[0] / DIM;           // 1560
    const int cache_len = in_sizes[3] / DIM;   // 9360

    float* q   = (float*)d_ws;
    float* k   = q + (size_t)S * DIM;
    float* v   = k + (size_t)S * DIM;
    float* att = v + (size_t)S * DIM;
    float* out = (float*)d_out;

    dim3 gb(16, 16);
    dim3 gg((DIM + 63) / 64, (S + 63) / 64);

    gemm_nt<<<gg, gb, 0, stream>>>(x, Wq, bq, q, S, DIM, DIM);
    gemm_nt<<<gg, gb, 0, stream>>>(x, Wk, bk, k, S, DIM, DIM);
    gemm_nt<<<gg, gb, 0, stream>>>(x, Wv, bv, v, S, DIM, DIM);

    norm_rope<<<dim3(S, 2), 256, 0, stream>>>(q, k, gq, gk, fcos, fsin, gh, gw, cs);

    attn_mfma<<<dim3((S + 63) / 64, NUM_HEADS), 256, 0, stream>>>(
        q, k, v, cache_k, cache_v, att, S, cache_len, gh, gw, cs, ge, le);

    gemm_nt<<<gg, gb, 0, stream>>>(att, Wo, bo, out, S, DIM, DIM);
}

// Round 7
// 816.708 us; speedup vs baseline: 5.6443x; 2.0385x over previous
//
#include <hip/hip_runtime.h>
#include <hip/hip_bf16.h>
#include <math.h>

#define NUM_HEADS 12
#define HEAD_DIM 128
#define DIM 1536
#define SINK_SIZE 1
#define MAX_ATT 1000000
#define EPS 1e-6f
#define SCALE 0.08838834764831845f  // 1/sqrt(128)

typedef __attribute__((ext_vector_type(8))) short short8;
typedef __attribute__((ext_vector_type(4))) float f32x4;

static __device__ __forceinline__ unsigned short f2b(float f) {
    __hip_bfloat16 h = __float2bfloat16(f);
    return __builtin_bit_cast(unsigned short, h);
}
static __device__ __forceinline__ float b2f(unsigned short u) {
    unsigned int v = ((unsigned int)u) << 16;
    return __builtin_bit_cast(float, v);
}

// ---- cache roll/append index math (shared by pack + attn) ----
struct Roll { int lsi, sink, nev, kstart, nkeys; bool rolled; };
static __device__ __forceinline__ Roll roll_math(int S, int cache_len,
                                                 const int* gh, const int* gw,
                                                 const int* cs, const int* ge,
                                                 const int* le) {
    Roll R;
    int fs = gh[0] * gw[0];
    R.sink = SINK_SIZE * fs;
    int current_end = cs[0] + S;
    int lei;
    R.nev = 0; R.rolled = false;
    if (current_end > ge[0] && S + le[0] > cache_len) {
        R.nev = S + le[0] - cache_len;
        lei = le[0] + current_end - ge[0] - R.nev;
        R.rolled = true;
    } else {
        lei = le[0] + current_end - ge[0];
    }
    R.lsi = lei - S;
    R.kstart = max(0, lei - MAX_ATT);
    R.nkeys = lei - R.kstart;
    return R;
}

// ---------------- fp32 GEMM (kept for o-proj): C = A @ W^T + bias ----------------
__global__ __launch_bounds__(256) void gemm_nt(const float* __restrict__ A,
                                               const float* __restrict__ W,
                                               const float* __restrict__ bias,
                                               float* __restrict__ C,
                                               int M, int N, int K) {
    __shared__ float As[16][65];
    __shared__ float Bs[16][65];
    const int tx = threadIdx.x, ty = threadIdx.y;
    const int t  = ty * 16 + tx;
    const int m0 = blockIdx.y * 64, n0 = blockIdx.x * 64;

    float acc[4][4] = {};
    const int lr = t >> 2;
    const int lc = (t & 3) * 4;

    for (int k0 = 0; k0 < K; k0 += 16) {
        float4 av = make_float4(0.f, 0.f, 0.f, 0.f);
        float4 bv = make_float4(0.f, 0.f, 0.f, 0.f);
        int m = m0 + lr;
        int n = n0 + lr;
        if (m < M) av = *(const float4*)&A[(size_t)m * K + k0 + lc];
        if (n < N) bv = *(const float4*)&W[(size_t)n * K + k0 + lc];
        As[lc + 0][lr] = av.x; As[lc + 1][lr] = av.y;
        As[lc + 2][lr] = av.z; As[lc + 3][lr] = av.w;
        Bs[lc + 0][lr] = bv.x; Bs[lc + 1][lr] = bv.y;
        Bs[lc + 2][lr] = bv.z; Bs[lc + 3][lr] = bv.w;
        __syncthreads();

        #pragma unroll
        for (int kk = 0; kk < 16; ++kk) {
            float a[4], b[4];
            #pragma unroll
            for (int i = 0; i < 4; ++i) a[i] = As[kk][ty + 16 * i];
            #pragma unroll
            for (int j = 0; j < 4; ++j) b[j] = Bs[kk][tx + 16 * j];
            #pragma unroll
            for (int i = 0; i < 4; ++i)
                #pragma unroll
                for (int j = 0; j < 4; ++j) acc[i][j] += a[i] * b[j];
        }
        __syncthreads();
    }

    #pragma unroll
    for (int i = 0; i < 4; ++i) {
        int m = m0 + ty + 16 * i;
        if (m >= M) continue;
        #pragma unroll
        for (int j = 0; j < 4; ++j) {
            int n = n0 + tx + 16 * j;
            if (n < N) C[(size_t)m * N + n] = acc[i][j] + bias[n];
        }
    }
}

// ---------------- bf16 MFMA GEMM (QKV): C = A @ W^T + bias ----------------
// Mirrors the HW-verified QK^T fragment paths from attn_mfma (round 5):
// A-frag row=lane&15 (wave-local), k=ds*32+8*(lane>>4); C: col=lane&15, row=4*(lane>>4)+reg.
__global__ __launch_bounds__(256) void gemm_nt_mfma(const float* __restrict__ A,
                                                    const float* __restrict__ W,
                                                    const float* __restrict__ bias,
                                                    float* __restrict__ C,
                                                    int M, int N, int K) {
    __shared__ __align__(16) unsigned short As[64][72];
    __shared__ __align__(16) unsigned short Bs[64][72];
    const int tid = threadIdx.x;
    const int l = tid & 63, wv = tid >> 6;
    const int g = l >> 4, c = l & 15;
    const int m0 = blockIdx.y * 64, n0 = blockIdx.x * 64;

    f32x4 acc[4];
    #pragma unroll
    for (int kb = 0; kb < 4; ++kb) acc[kb] = 0.f;

    const int srow = tid >> 2;            // 0..63 tile row
    const int skq  = (tid & 3) * 16;      // 16 k-values per thread

    for (int k0 = 0; k0 < K; k0 += 64) {
        // stage A tile [64 m][64 k] -> bf16
        {
            int m = m0 + srow;
            short8 w0 = 0, w1 = 0;
            if (m < M) {
                const float* src = &A[(size_t)m * K + k0 + skq];
                #pragma unroll
                for (int i = 0; i < 8; ++i) w0[i] = (short)f2b(src[i]);
                #pragma unroll
                for (int i = 0; i < 8; ++i) w1[i] = (short)f2b(src[8 + i]);
            }
            *(short8*)&As[srow][skq] = w0;
            *(short8*)&As[srow][skq + 8] = w1;
        }
        // stage B tile [64 n][64 k] -> bf16  (W rows are output cols)
        {
            int n = n0 + srow;
            short8 w0 = 0, w1 = 0;
            if (n < N) {
                const float* src = &W[(size_t)n * K + k0 + skq];
                #pragma unroll
                for (int i = 0; i < 8; ++i) w0[i] = (short)f2b(src[i]);
                #pragma unroll
                for (int i = 0; i < 8; ++i) w1[i] = (short)f2b(src[8 + i]);
            }
            *(short8*)&Bs[srow][skq] = w0;
            *(short8*)&Bs[srow][skq + 8] = w1;
        }
        __syncthreads();

        short8 af0 = *(const short8*)&As[wv * 16 + c][g * 8];
        short8 af1 = *(const short8*)&As[wv * 16 + c][32 + g * 8];
        #pragma unroll
        for (int kb = 0; kb < 4; ++kb) {
            short8 bf0 = *(const short8*)&Bs[kb * 16 + c][g * 8];
            short8 bf1 = *(const short8*)&Bs[kb * 16 + c][32 + g * 8];
            acc[kb] = __builtin_amdgcn_mfma_f32_16x16x32_bf16(af0, bf0, acc[kb], 0, 0, 0);
            acc[kb] = __builtin_amdgcn_mfma_f32_16x16x32_bf16(af1, bf1, acc[kb], 0, 0, 0);
        }
        __syncthreads();
    }

    #pragma unroll
    for (int r = 0; r < 4; ++r) {
        int m = m0 + wv * 16 + 4 * g + r;
        if (m >= M) continue;
        #pragma unroll
        for (int kb = 0; kb < 4; ++kb) {
            int n = n0 + kb * 16 + c;
            if (n < N) C[(size_t)m * N + n] = acc[kb][r] + bias[n];
        }
    }
}

// ------------- RMSNorm + RoPE, in place, one block per (token, q|k) -------------
__global__ __launch_bounds__(256) void norm_rope(float* __restrict__ qbuf,
                                                 float* __restrict__ kbuf,
                                                 const float* __restrict__ gq,
                                                 const float* __restrict__ gk,
                                                 const float* __restrict__ fcos,
                                                 const float* __restrict__ fsin,
                                                 const int* __restrict__ gh,
                                                 const int* __restrict__ gw,
                                                 const int* __restrict__ cs) {
    const int s = blockIdx.x;
    float* buf = blockIdx.y ? kbuf : qbuf;
    const float* g = blockIdx.y ? gk : gq;
    __shared__ float row[DIM];
    __shared__ float red[4];
    const int t = threadIdx.x;
    float* p = buf + (size_t)s * DIM;

    float vals[6];
    float ss = 0.f;
    #pragma unroll
    for (int i = 0; i < 6; ++i) {
        vals[i] = p[t + 256 * i];
        ss += vals[i] * vals[i];
    }
    #pragma unroll
    for (int off = 32; off > 0; off >>= 1) ss += __shfl_down(ss, off, 64);
    if ((t & 63) == 0) red[t >> 6] = ss;
    __syncthreads();
    float tot = red[0] + red[1] + red[2] + red[3];
    float rr = rsqrtf(tot / (float)DIM + EPS);
    #pragma unroll
    for (int i = 0; i < 6; ++i) row[t + 256 * i] = vals[i] * rr * g[t + 256 * i];
    __syncthreads();

    const int fs = gh[0] * gw[0];
    const int sf = cs[0] / fs;
    const int fi = s / fs;
    const int rem = s - fi * fs;
    const int hi = rem / gw[0];
    const int wi = rem - hi * gw[0];

    #pragma unroll
    for (int r = 0; r < 3; ++r) {
        int pi = t + 256 * r;
        int h = pi >> 6, j = pi & 63;
        int trow = (j < 22) ? (sf + fi) : ((j < 43) ? hi : wi);
        float c = fcos[trow * 64 + j];
        float sn = fsin[trow * 64 + j];
        float re = row[h * 128 + 2 * j];
        float im = row[h * 128 + 2 * j + 1];
        p[h * 128 + 2 * j]     = re * c - im * sn;
        p[h * 128 + 2 * j + 1] = re * sn + im * c;
    }
}

// ---------------- pack K/V -> bf16 [head][key][128], remap resolved ----------------
__global__ __launch_bounds__(256) void pack_kv(const float* __restrict__ fresh,
                                               const float* __restrict__ cache,
                                               unsigned int* __restrict__ dst,
                                               int S, int cache_len, int KS,
                                               const int* __restrict__ gh,
                                               const int* __restrict__ gw,
                                               const int* __restrict__ cs,
                                               const int* __restrict__ ge,
                                               const int* __restrict__ le) {
    Roll R = roll_math(S, cache_len, gh, gw, cs, ge, le);
    const int head = blockIdx.y;
    const int j = blockIdx.x * 4 + (threadIdx.x >> 6);
    const int lane = threadIdx.x & 63;
    unsigned int out = 0;
    if (j < R.nkeys) {
        int a = R.kstart + j;
        const float* src;
        if (a >= R.lsi) src = fresh + (size_t)(a - R.lsi) * DIM;
        else {
            int srow = (R.rolled && a >= R.sink) ? a + R.nev : a;
            src = cache + (size_t)srow * DIM;
        }
        float2 vv = *(const float2*)(src + head * HEAD_DIM + lane * 2);
        out = (unsigned)f2b(vv.x) | ((unsigned)f2b(vv.y) << 16);
    }
    dst[((size_t)head * KS + j) * 64 + lane] = out;   // zero-fill pad keys
}

// -------------------- split-K bf16 MFMA flash attention --------------------
__global__ __launch_bounds__(256) void attn_mfma(const float* __restrict__ qbuf,
                                                 const unsigned short* __restrict__ Kb,
                                                 const unsigned short* __restrict__ Vb,
                                                 float* __restrict__ Opart,
                                                 float* __restrict__ Mpart,
                                                 float* __restrict__ Lpart,
                                                 int S, int cache_len, int KS, int nsplit,
                                                 const int* __restrict__ gh,
                                                 const int* __restrict__ gw,
                                                 const int* __restrict__ cs,
                                                 const int* __restrict__ ge,
                                                 const int* __restrict__ le) {
    Roll R = roll_math(S, cache_len, gh, gw, cs, ge, le);
    const int nkeys = R.nkeys;

    const int head = blockIdx.y;
    const int split = blockIdx.z;
    const int q0 = blockIdx.x * 64;
    const int tid = threadIdx.x;
    const int l = tid & 63, wv = tid >> 6;
    const int g = l >> 4, c = l & 15;

    // split bounds (64-aligned chunks)
    const int chunk = ((nkeys + nsplit * 64 - 1) / (nsplit * 64)) * 64;
    const int j_lo = split * chunk;
    const int j_hi = min(nkeys, j_lo + chunk);

    __shared__ __align__(16) unsigned short Ks[64][136];   // [key][d]
    __shared__ __align__(16) unsigned short Vt[128][72];   // [d][key]
    __shared__ __align__(16) unsigned short Pl[4][16][72]; // [wave][q][key]

    // Q A-fragments: row=c, k=ds*32+8g+j
    short8 qf[4];
    {
        int qrow = q0 + wv * 16 + c;
        const float* qp = qbuf + (size_t)qrow * DIM + head * HEAD_DIM + g * 8;
        #pragma unroll
        for (int ds = 0; ds < 4; ++ds) {
            short8 w = 0;
            if (qrow < S) {
                float4 a4 = *(const float4*)(qp + ds * 32);
                float4 b4 = *(const float4*)(qp + ds * 32 + 4);
                w[0] = (short)f2b(a4.x); w[1] = (short)f2b(a4.y);
                w[2] = (short)f2b(a4.z); w[3] = (short)f2b(a4.w);
                w[4] = (short)f2b(b4.x); w[5] = (short)f2b(b4.y);
                w[6] = (short)f2b(b4.z); w[7] = (short)f2b(b4.w);
            }
            qf[ds] = w;
        }
    }

    f32x4 accO[8];
    #pragma unroll
    for (int nb = 0; nb < 8; ++nb) accO[nb] = 0.f;
    float m_r[4], l_r[4];
    #pragma unroll
    for (int r = 0; r < 4; ++r) { m_r[r] = -INFINITY; l_r[r] = 0.f; }

    const int kkey = tid >> 2, kdb = (tid & 3) * 32;   // K staging: 1 key, 32 d
    const int vkp = tid & 31, vdg = tid >> 5;          // V staging: 2 keys, 16 d

    for (int j0 = j_lo; j0 < j_hi; j0 += 64) {
        // ---- stage K tile from packed bf16 (zero-padded to KS) ----
        {
            const unsigned short* src = Kb + ((size_t)head * KS + j0 + kkey) * 128 + kdb;
            short8 w0 = *(const short8*)(src);
            short8 w1 = *(const short8*)(src + 8);
            short8 w2 = *(const short8*)(src + 16);
            short8 w3 = *(const short8*)(src + 24);
            *(short8*)&Ks[kkey][kdb]      = w0;
            *(short8*)&Ks[kkey][kdb + 8]  = w1;
            *(short8*)&Ks[kkey][kdb + 16] = w2;
            *(short8*)&Ks[kkey][kdb + 24] = w3;
        }
        // ---- stage V tile transposed: Vt[d][key], packed pair writes ----
        {
            const unsigned short* sa = Vb + ((size_t)head * KS + j0 + 2 * vkp) * 128 + vdg * 16;
            short8 a0 = *(const short8*)(sa);
            short8 a1 = *(const short8*)(sa + 8);
            short8 b0 = *(const short8*)(sa + 128);
            short8 b1 = *(const short8*)(sa + 136);
            #pragma unroll
            for (int i = 0; i < 8; ++i) {
                unsigned int lo = (unsigned)(unsigned short)a0[i] |
                                  ((unsigned)(unsigned short)b0[i] << 16);
                *(unsigned int*)&Vt[vdg * 16 + i][2 * vkp] = lo;
                unsigned int hi = (unsigned)(unsigned short)a1[i] |
                                  ((unsigned)(unsigned short)b1[i] << 16);
                *(unsigned int*)&Vt[vdg * 16 + 8 + i][2 * vkp] = hi;
            }
        }
        __syncthreads();

        // ---- QK^T ----
        f32x4 accS[4];
        #pragma unroll
        for (int kb = 0; kb < 4; ++kb) accS[kb] = 0.f;
        #pragma unroll
        for (int kb = 0; kb < 4; ++kb) {
            #pragma unroll
            for (int ds = 0; ds < 4; ++ds) {
                short8 kf = *(const short8*)&Ks[kb * 16 + c][ds * 32 + g * 8];
                accS[kb] = __builtin_amdgcn_mfma_f32_16x16x32_bf16(qf[ds], kf, accS[kb], 0, 0, 0);
            }
        }

        // ---- online softmax ----
        bool maskk[4];
        #pragma unroll
        for (int kb = 0; kb < 4; ++kb) maskk[kb] = (j0 + kb * 16 + c) >= j_hi;

        #pragma unroll
        for (int r = 0; r < 4; ++r) {
            float sv[4];
            #pragma unroll
            for (int kb = 0; kb < 4; ++kb)
                sv[kb] = maskk[kb] ? -INFINITY : accS[kb][r] * SCALE;
            float mt = fmaxf(fmaxf(sv[0], sv[1]), fmaxf(sv[2], sv[3]));
            #pragma unroll
            for (int off = 1; off < 16; off <<= 1)
                mt = fmaxf(mt, __shfl_xor(mt, off, 64));
            float mn = fmaxf(m_r[r], mt);
            float fr = __expf(m_r[r] - mn);
            m_r[r] = mn;
            float ls = 0.f;
            #pragma unroll
            for (int kb = 0; kb < 4; ++kb) {
                float pv = __expf(sv[kb] - mn);
                unsigned short pb = f2b(pv);
                ls += b2f(pb);
                Pl[wv][4 * g + r][kb * 16 + c] = pb;
            }
            #pragma unroll
            for (int off = 1; off < 16; off <<= 1)
                ls += __shfl_xor(ls, off, 64);
            l_r[r] = l_r[r] * fr + ls;
            #pragma unroll
            for (int nb = 0; nb < 8; ++nb) accO[nb][r] *= fr;
        }

        asm volatile("s_waitcnt lgkmcnt(0)" ::: "memory");
        __builtin_amdgcn_sched_barrier(0);

        // ---- PV ----
        short8 pa0 = *(const short8*)&Pl[wv][c][g * 8];
        short8 pa1 = *(const short8*)&Pl[wv][c][32 + g * 8];
        #pragma unroll
        for (int nb = 0; nb < 8; ++nb) {
            short8 vb0 = *(const short8*)&Vt[nb * 16 + c][g * 8];
            short8 vb1 = *(const short8*)&Vt[nb * 16 + c][32 + g * 8];
            accO[nb] = __builtin_amdgcn_mfma_f32_16x16x32_bf16(pa0, vb0, accO[nb], 0, 0, 0);
            accO[nb] = __builtin_amdgcn_mfma_f32_16x16x32_bf16(pa1, vb1, accO[nb], 0, 0, 0);
        }
        __syncthreads();
    }

    // ---- epilogue: unnormalized partials ----
    #pragma unroll
    for (int r = 0; r < 4; ++r) {
        int row = q0 + wv * 16 + 4 * g + r;
        if (row >= S) continue;
        size_t rowbase = (((size_t)split * S + row) * NUM_HEADS + head);
        #pragma unroll
        for (int nb = 0; nb < 8; ++nb)
            Opart[rowbase * HEAD_DIM + nb * 16 + c] = accO[nb][r];
        if (c == 0) {
            Mpart[rowbase] = m_r[r];
            Lpart[rowbase] = l_r[r];
        }
    }
}

// -------------------- combine split-K partials --------------------
__global__ __launch_bounds__(256) void attn_combine(const float* __restrict__ Opart,
                                                    const float* __restrict__ Mpart,
                                                    const float* __restrict__ Lpart,
                                                    float* __restrict__ att,
                                                    int S, int nsplit) {
    const int s = blockIdx.x;
    const int h = blockIdx.y * 2 + (threadIdx.x >> 7);
    const int d = threadIdx.x & 127;

    float mstar = -INFINITY;
    for (int i = 0; i < nsplit; ++i)
        mstar = fmaxf(mstar, Mpart[((size_t)i * S + s) * NUM_HEADS + h]);
    float L = 0.f, o = 0.f;
    for (int i = 0; i < nsplit; ++i) {
        size_t rb = ((size_t)i * S + s) * NUM_HEADS + h;
        float w = __expf(Mpart[rb] - mstar);
        L += w * Lpart[rb];
        o += w * Opart[rb * HEAD_DIM + d];
    }
    att[(size_t)s * DIM + h * HEAD_DIM + d] = o / L;
}

// ----------------------------------- launch -----------------------------------
extern "C" void kernel_launch(void* const* d_in, const int* in_sizes, int n_in,
                              void* d_out, int out_size, void* d_ws, size_t ws_size,
                              hipStream_t stream) {
    const float* x       = (const float*)d_in[0];
    const float* fcos    = (const float*)d_in[1];
    const float* fsin    = (const float*)d_in[2];
    const float* cache_k = (const float*)d_in[3];
    const float* cache_v = (const float*)d_in[4];
    const float* Wq      = (const float*)d_in[5];
    const float* bq      = (const float*)d_in[6];
    const float* Wk      = (const float*)d_in[7];
    const float* bk      = (const float*)d_in[8];
    const float* Wv      = (const float*)d_in[9];
    const float* bv      = (const float*)d_in[10];
    const float* Wo      = (const float*)d_in[11];
    const float* bo      = (const float*)d_in[12];
    const float* gq      = (const float*)d_in[13];
    const float* gk      = (const float*)d_in[14];
    const int* gh        = (const int*)d_in[16];
    const int* gw        = (const int*)d_in[17];
    const int* cs        = (const int*)d_in[18];
    const int* ge        = (const int*)d_in[19];
    const int* le        = (const int*)d_in[20];

    const int S = in_sizes[0] / DIM;           // 1560
    const int cache_len = in_sizes[3] / DIM;   // 9360
    const int KS = ((cache_len + 63) / 64) * 64; // 9408 (padded key stride)

    const size_t SD = (size_t)S * DIM;
    float* q   = (float*)d_ws;
    float* k   = q + SD;
    float* v   = k + SD;
    float* att = v + SD;
    unsigned int* Kb = (unsigned int*)(att + SD);          // [12][KS][64] u32 (bf16x2)
    unsigned int* Vb = Kb + (size_t)NUM_HEADS * KS * 64;
    float* Opart = (float*)(Vb + (size_t)NUM_HEADS * KS * 64);

    // choose split factor from available workspace (constant across calls)
    size_t base_bytes = (size_t)((char*)Opart - (char*)d_ws);
    size_t per_split  = SD * sizeof(float) + (size_t)S * NUM_HEADS * 2 * sizeof(float);
    int nsplit = 1;
    if (ws_size > base_bytes + per_split)
        nsplit = (int)((ws_size - base_bytes) / per_split);
    if (nsplit > 4) nsplit = 4;
    if (nsplit < 1) nsplit = 1;
    float* Mpart = Opart + (size_t)nsplit * SD;
    float* Lpart = Mpart + (size_t)nsplit * S * NUM_HEADS;

    float* out = (float*)d_out;

    dim3 gmm(DIM / 64, (S + 63) / 64);
    gemm_nt_mfma<<<gmm, 256, 0, stream>>>(x, Wq, bq, q, S, DIM, DIM);
    gemm_nt_mfma<<<gmm, 256, 0, stream>>>(x, Wk, bk, k, S, DIM, DIM);
    gemm_nt_mfma<<<gmm, 256, 0, stream>>>(x, Wv, bv, v, S, DIM, DIM);

    norm_rope<<<dim3(S, 2), 256, 0, stream>>>(q, k, gq, gk, fcos, fsin, gh, gw, cs);

    dim3 gpk(KS / 4, NUM_HEADS);
    pack_kv<<<gpk, 256, 0, stream>>>(k, cache_k, Kb, S, cache_len, KS, gh, gw, cs, ge, le);
    pack_kv<<<gpk, 256, 0, stream>>>(v, cache_v, Vb, S, cache_len, KS, gh, gw, cs, ge, le);

    attn_mfma<<<dim3((S + 63) / 64, NUM_HEADS, nsplit), 256, 0, stream>>>(
        q, (const unsigned short*)Kb, (const unsigned short*)Vb,
        Opart, Mpart, Lpart, S, cache_len, KS, nsplit, gh, gw, cs, ge, le);

    attn_combine<<<dim3(S, NUM_HEADS / 2), 256, 0, stream>>>(
        Opart, Mpart, Lpart, att, S, nsplit);

    dim3 gb(16, 16);
    gemm_nt<<<dim3(DIM / 64, (S + 63) / 64), gb, 0, stream>>>(att, Wo, bo, out, S, DIM, DIM);
}

// Round 8
// 599.584 us; speedup vs baseline: 7.6882x; 1.3621x over previous
//
#include <hip/hip_runtime.h>
#include <hip/hip_bf16.h>
#include <math.h>

#define NUM_HEADS 12
#define HEAD_DIM 128
#define DIM 1536
#define SINK_SIZE 1
#define MAX_ATT 1000000
#define EPS 1e-6f
#define SCALE 0.08838834764831845f  // 1/sqrt(128)
#define RESCALE_THR 8.0f

typedef __attribute__((ext_vector_type(8))) short short8;
typedef __attribute__((ext_vector_type(4))) float f32x4;

static __device__ __forceinline__ unsigned short f2b(float f) {
    __hip_bfloat16 h = __float2bfloat16(f);
    return __builtin_bit_cast(unsigned short, h);
}
static __device__ __forceinline__ float b2f(unsigned short u) {
    unsigned int v = ((unsigned int)u) << 16;
    return __builtin_bit_cast(float, v);
}

// ---- cache roll/append index math ----
struct Roll { int lsi, sink, nev, kstart, nkeys; bool rolled; };
static __device__ __forceinline__ Roll roll_math(int S, int cache_len,
                                                 const int* gh, const int* gw,
                                                 const int* cs, const int* ge,
                                                 const int* le) {
    Roll R;
    int fs = gh[0] * gw[0];
    R.sink = SINK_SIZE * fs;
    int current_end = cs[0] + S;
    int lei;
    R.nev = 0; R.rolled = false;
    if (current_end > ge[0] && S + le[0] > cache_len) {
        R.nev = S + le[0] - cache_len;
        lei = le[0] + current_end - ge[0] - R.nev;
        R.rolled = true;
    } else {
        lei = le[0] + current_end - ge[0];
    }
    R.lsi = lei - S;
    R.kstart = max(0, lei - MAX_ATT);
    R.nkeys = lei - R.kstart;
    return R;
}

__device__ __forceinline__ const float* key_src(const float* cache, const float* fresh,
                                                int a, const Roll& R) {
    if (a >= R.lsi) return fresh + (size_t)(a - R.lsi) * DIM;
    int srow = (R.rolled && a >= R.sink) ? a + R.nev : a;
    return cache + (size_t)srow * DIM;
}

// ---------------- fp32 -> bf16 matrix pack (vectorized, grid-stride) ----------------
__global__ __launch_bounds__(256) void pack_mat(const float* __restrict__ src,
                                                unsigned short* __restrict__ dst,
                                                long n8) {   // n/8 groups
    long stride = (long)gridDim.x * 256;
    for (long i = blockIdx.x * 256L + threadIdx.x; i < n8; i += stride) {
        float4 a = *(const float4*)&src[i * 8];
        float4 b = *(const float4*)&src[i * 8 + 4];
        short8 w;
        w[0] = (short)f2b(a.x); w[1] = (short)f2b(a.y);
        w[2] = (short)f2b(a.z); w[3] = (short)f2b(a.w);
        w[4] = (short)f2b(b.x); w[5] = (short)f2b(b.y);
        w[6] = (short)f2b(b.z); w[7] = (short)f2b(b.w);
        *(short8*)&dst[i * 8] = w;
    }
}

// ---------------- bf16 MFMA GEMM: C[M][N] = A[M][K] @ W[N][K]^T + bias ----------------
// Fragment paths HW-verified (rounds 5/7): A row=lane&15 wave-local, k=ds*32+8*(lane>>4);
// C: col=lane&15, row=4*(lane>>4)+reg.
__global__ __launch_bounds__(256) void gemm_bf16_nt(const unsigned short* __restrict__ A,
                                                    const unsigned short* __restrict__ W,
                                                    const float* __restrict__ bias,
                                                    float* __restrict__ C,
                                                    int M, int N, int K) {
    __shared__ __align__(16) unsigned short As[64][72];
    __shared__ __align__(16) unsigned short Bs[64][72];
    const int tid = threadIdx.x;
    const int wv = tid >> 6;
    const int g = (tid & 63) >> 4, c = tid & 15;
    const int m0 = blockIdx.y * 64, n0 = blockIdx.x * 64;

    f32x4 acc[4];
    #pragma unroll
    for (int kb = 0; kb < 4; ++kb) acc[kb] = 0.f;

    const int srow = tid >> 2;            // 0..63 tile row
    const int skq  = (tid & 3) * 16;      // 16 k per thread

    for (int k0 = 0; k0 < K; k0 += 64) {
        {
            int m = m0 + srow;
            short8 w0 = 0, w1 = 0;
            if (m < M) {
                const unsigned short* src = &A[(size_t)m * K + k0 + skq];
                w0 = *(const short8*)(src);
                w1 = *(const short8*)(src + 8);
            }
            *(short8*)&As[srow][skq] = w0;
            *(short8*)&As[srow][skq + 8] = w1;
        }
        {
            int n = n0 + srow;   // N multiple of 64 here, no guard needed but keep cheap
            const unsigned short* src = &W[(size_t)n * K + k0 + skq];
            *(short8*)&Bs[srow][skq] = *(const short8*)(src);
            *(short8*)&Bs[srow][skq + 8] = *(const short8*)(src + 8);
        }
        __syncthreads();

        short8 af0 = *(const short8*)&As[wv * 16 + c][g * 8];
        short8 af1 = *(const short8*)&As[wv * 16 + c][32 + g * 8];
        #pragma unroll
        for (int kb = 0; kb < 4; ++kb) {
            short8 bf0 = *(const short8*)&Bs[kb * 16 + c][g * 8];
            short8 bf1 = *(const short8*)&Bs[kb * 16 + c][32 + g * 8];
            acc[kb] = __builtin_amdgcn_mfma_f32_16x16x32_bf16(af0, bf0, acc[kb], 0, 0, 0);
            acc[kb] = __builtin_amdgcn_mfma_f32_16x16x32_bf16(af1, bf1, acc[kb], 0, 0, 0);
        }
        __syncthreads();
    }

    #pragma unroll
    for (int r = 0; r < 4; ++r) {
        int m = m0 + wv * 16 + 4 * g + r;
        if (m >= M) continue;
        #pragma unroll
        for (int kb = 0; kb < 4; ++kb) {
            int n = n0 + kb * 16 + c;
            C[(size_t)m * N + n] = acc[kb][r] + bias[n];
        }
    }
}

// ------------- RMSNorm + RoPE, in place, one block per (token, q|k) -------------
__global__ __launch_bounds__(256) void norm_rope(float* __restrict__ qbuf,
                                                 float* __restrict__ kbuf,
                                                 const float* __restrict__ gq,
                                                 const float* __restrict__ gk,
                                                 const float* __restrict__ fcos,
                                                 const float* __restrict__ fsin,
                                                 const int* __restrict__ gh,
                                                 const int* __restrict__ gw,
                                                 const int* __restrict__ cs) {
    const int s = blockIdx.x;
    float* buf = blockIdx.y ? kbuf : qbuf;
    const float* g = blockIdx.y ? gk : gq;
    __shared__ float row[DIM];
    __shared__ float red[4];
    const int t = threadIdx.x;
    float* p = buf + (size_t)s * DIM;

    float vals[6];
    float ss = 0.f;
    #pragma unroll
    for (int i = 0; i < 6; ++i) {
        vals[i] = p[t + 256 * i];
        ss += vals[i] * vals[i];
    }
    #pragma unroll
    for (int off = 32; off > 0; off >>= 1) ss += __shfl_down(ss, off, 64);
    if ((t & 63) == 0) red[t >> 6] = ss;
    __syncthreads();
    float tot = red[0] + red[1] + red[2] + red[3];
    float rr = rsqrtf(tot / (float)DIM + EPS);
    #pragma unroll
    for (int i = 0; i < 6; ++i) row[t + 256 * i] = vals[i] * rr * g[t + 256 * i];
    __syncthreads();

    const int fs = gh[0] * gw[0];
    const int sf = cs[0] / fs;
    const int fi = s / fs;
    const int rem = s - fi * fs;
    const int hi = rem / gw[0];
    const int wi = rem - hi * gw[0];

    #pragma unroll
    for (int r = 0; r < 3; ++r) {
        int pi = t + 256 * r;
        int h = pi >> 6, j = pi & 63;
        int trow = (j < 22) ? (sf + fi) : ((j < 43) ? hi : wi);
        float c = fcos[trow * 64 + j];
        float sn = fsin[trow * 64 + j];
        float re = row[h * 128 + 2 * j];
        float im = row[h * 128 + 2 * j + 1];
        p[h * 128 + 2 * j]     = re * c - im * sn;
        p[h * 128 + 2 * j + 1] = re * sn + im * c;
    }
}

// ---------------- pack K -> bf16 [head][key][128], remap resolved ----------------
__global__ __launch_bounds__(256) void pack_kv(const float* __restrict__ fresh,
                                               const float* __restrict__ cache,
                                               unsigned int* __restrict__ dst,
                                               int S, int cache_len, int KS,
                                               const int* __restrict__ gh,
                                               const int* __restrict__ gw,
                                               const int* __restrict__ cs,
                                               const int* __restrict__ ge,
                                               const int* __restrict__ le) {
    Roll R = roll_math(S, cache_len, gh, gw, cs, ge, le);
    const int head = blockIdx.y;
    const int j = blockIdx.x * 4 + (threadIdx.x >> 6);
    const int lane = threadIdx.x & 63;
    unsigned int out = 0;
    if (j < R.nkeys) {
        const float* src = key_src(cache, fresh, R.kstart + j, R);
        float2 vv = *(const float2*)(src + head * HEAD_DIM + lane * 2);
        out = (unsigned)f2b(vv.x) | ((unsigned)f2b(vv.y) << 16);
    }
    dst[((size_t)head * KS + j) * 64 + lane] = out;
}

// ---------------- pack V TRANSPOSED -> bf16 [head][d=128][KS] ----------------
__global__ __launch_bounds__(256) void pack_vt(const float* __restrict__ fresh,
                                               const float* __restrict__ cache,
                                               unsigned short* __restrict__ dst,
                                               int S, int cache_len, int KS,
                                               const int* __restrict__ gh,
                                               const int* __restrict__ gw,
                                               const int* __restrict__ cs,
                                               const int* __restrict__ ge,
                                               const int* __restrict__ le) {
    Roll R = roll_math(S, cache_len, gh, gw, cs, ge, le);
    const int head = blockIdx.y;
    const int j0 = blockIdx.x * 64;
    const int tid = threadIdx.x;
    __shared__ __align__(16) unsigned short Lt[128][72];

    const int kp = tid & 31, dg = tid >> 5;   // 2 keys, 16 d per thread
    int ja = j0 + 2 * kp, jb = ja + 1;
    float ra[16], rb[16];
    #pragma unroll
    for (int i = 0; i < 16; ++i) { ra[i] = 0.f; rb[i] = 0.f; }
    if (ja < R.nkeys) {
        const float* sa = key_src(cache, fresh, R.kstart + ja, R) + head * HEAD_DIM + dg * 16;
        #pragma unroll
        for (int qq = 0; qq < 4; ++qq) {
            float4 t4 = *(const float4*)(sa + qq * 4);
            ra[qq*4+0]=t4.x; ra[qq*4+1]=t4.y; ra[qq*4+2]=t4.z; ra[qq*4+3]=t4.w;
        }
    }
    if (jb < R.nkeys) {
        const float* sb = key_src(cache, fresh, R.kstart + jb, R) + head * HEAD_DIM + dg * 16;
        #pragma unroll
        for (int qq = 0; qq < 4; ++qq) {
            float4 t4 = *(const float4*)(sb + qq * 4);
            rb[qq*4+0]=t4.x; rb[qq*4+1]=t4.y; rb[qq*4+2]=t4.z; rb[qq*4+3]=t4.w;
        }
    }
    #pragma unroll
    for (int i = 0; i < 16; ++i) {
        unsigned int pk = (unsigned)f2b(ra[i]) | ((unsigned)f2b(rb[i]) << 16);
        *(unsigned int*)&Lt[dg * 16 + i][2 * kp] = pk;
    }
    __syncthreads();

    const int drow = tid >> 1, half = tid & 1;
    const unsigned short* srcr = &Lt[drow][half * 32];
    unsigned short* d_ = dst + ((size_t)head * 128 + drow) * KS + j0 + half * 32;
    *(short8*)(d_)      = *(const short8*)(srcr);
    *(short8*)(d_ + 8)  = *(const short8*)(srcr + 8);
    *(short8*)(d_ + 16) = *(const short8*)(srcr + 16);
    *(short8*)(d_ + 24) = *(const short8*)(srcr + 24);
}

// -------------------- split-K bf16 MFMA flash attention --------------------
__global__ __launch_bounds__(256) void attn_mfma(const float* __restrict__ qbuf,
                                                 const unsigned short* __restrict__ Kb,
                                                 const unsigned short* __restrict__ Vb,
                                                 float* __restrict__ Opart,
                                                 float* __restrict__ Mpart,
                                                 float* __restrict__ Lpart,
                                                 int S, int cache_len, int KS, int nsplit,
                                                 const int* __restrict__ gh,
                                                 const int* __restrict__ gw,
                                                 const int* __restrict__ cs,
                                                 const int* __restrict__ ge,
                                                 const int* __restrict__ le) {
    Roll R = roll_math(S, cache_len, gh, gw, cs, ge, le);
    const int nkeys = R.nkeys;

    const int head = blockIdx.y;
    const int split = blockIdx.z;
    const int q0 = blockIdx.x * 64;
    const int tid = threadIdx.x;
    const int wv = tid >> 6;
    const int g = (tid & 63) >> 4, c = tid & 15;

    const int chunk = ((nkeys + nsplit * 64 - 1) / (nsplit * 64)) * 64;
    const int j_lo = split * chunk;
    const int j_hi = min(nkeys, j_lo + chunk);

    __shared__ __align__(16) unsigned short Ks[64][136];   // [key][d]
    __shared__ __align__(16) unsigned short Vt[128][72];   // [d][key]
    __shared__ __align__(16) unsigned short Pl[4][16][72]; // [wave][q][key]

    // Q A-fragments: row=c, k=ds*32+8g+j
    short8 qf[4];
    {
        int qrow = q0 + wv * 16 + c;
        const float* qp = qbuf + (size_t)qrow * DIM + head * HEAD_DIM + g * 8;
        #pragma unroll
        for (int ds = 0; ds < 4; ++ds) {
            short8 w = 0;
            if (qrow < S) {
                float4 a4 = *(const float4*)(qp + ds * 32);
                float4 b4 = *(const float4*)(qp + ds * 32 + 4);
                w[0]=(short)f2b(a4.x); w[1]=(short)f2b(a4.y);
                w[2]=(short)f2b(a4.z); w[3]=(short)f2b(a4.w);
                w[4]=(short)f2b(b4.x); w[5]=(short)f2b(b4.y);
                w[6]=(short)f2b(b4.z); w[7]=(short)f2b(b4.w);
            }
            qf[ds] = w;
        }
    }

    f32x4 accO[8];
    #pragma unroll
    for (int nb = 0; nb < 8; ++nb) accO[nb] = 0.f;
    float m_r[4], l_r[4];
    #pragma unroll
    for (int r = 0; r < 4; ++r) { m_r[r] = -INFINITY; l_r[r] = 0.f; }

    const int kkey = tid >> 2, kdb = (tid & 3) * 32;   // K staging
    const int vrow = tid >> 1, vhalf = tid & 1;        // V staging (direct copy)

    for (int j0 = j_lo; j0 < j_hi; j0 += 64) {
        // ---- stage K tile (direct b128 copies) ----
        {
            const unsigned short* src = Kb + ((size_t)head * KS + j0 + kkey) * 128 + kdb;
            *(short8*)&Ks[kkey][kdb]      = *(const short8*)(src);
            *(short8*)&Ks[kkey][kdb + 8]  = *(const short8*)(src + 8);
            *(short8*)&Ks[kkey][kdb + 16] = *(const short8*)(src + 16);
            *(short8*)&Ks[kkey][kdb + 24] = *(const short8*)(src + 24);
        }
        // ---- stage V tile (pre-transposed, direct b128 copies) ----
        {
            const unsigned short* src = Vb + ((size_t)head * 128 + vrow) * KS + j0 + vhalf * 32;
            *(short8*)&Vt[vrow][vhalf * 32]      = *(const short8*)(src);
            *(short8*)&Vt[vrow][vhalf * 32 + 8]  = *(const short8*)(src + 8);
            *(short8*)&Vt[vrow][vhalf * 32 + 16] = *(const short8*)(src + 16);
            *(short8*)&Vt[vrow][vhalf * 32 + 24] = *(const short8*)(src + 24);
        }
        __syncthreads();

        // ---- QK^T ----
        f32x4 accS[4];
        #pragma unroll
        for (int kb = 0; kb < 4; ++kb) accS[kb] = 0.f;
        #pragma unroll
        for (int kb = 0; kb < 4; ++kb) {
            #pragma unroll
            for (int ds = 0; ds < 4; ++ds) {
                short8 kf = *(const short8*)&Ks[kb * 16 + c][ds * 32 + g * 8];
                accS[kb] = __builtin_amdgcn_mfma_f32_16x16x32_bf16(qf[ds], kf, accS[kb], 0, 0, 0);
            }
        }

        // ---- scale + mask ----
        #pragma unroll
        for (int kb = 0; kb < 4; ++kb) {
            bool mk = (j0 + kb * 16 + c) >= j_hi;
            #pragma unroll
            for (int r = 0; r < 4; ++r)
                accS[kb][r] = mk ? -INFINITY : accS[kb][r] * SCALE;
        }

        // ---- tile max + defer-max rescale (T13) ----
        float mt4[4];
        bool need = false;
        #pragma unroll
        for (int r = 0; r < 4; ++r) {
            float mt = fmaxf(fmaxf(accS[0][r], accS[1][r]), fmaxf(accS[2][r], accS[3][r]));
            #pragma unroll
            for (int off = 1; off < 16; off <<= 1)
                mt = fmaxf(mt, __shfl_xor(mt, off, 64));
            mt4[r] = mt;
            need = need || (mt > m_r[r] + RESCALE_THR);
        }
        if (__any(need)) {
            #pragma unroll
            for (int r = 0; r < 4; ++r) {
                float mn = fmaxf(m_r[r], mt4[r]);
                float fr = __expf(m_r[r] - mn);
                m_r[r] = mn;
                l_r[r] *= fr;
                #pragma unroll
                for (int nb = 0; nb < 8; ++nb) accO[nb][r] *= fr;
            }
        }

        // ---- P = exp(S - m), bf16-consistent l accumulation ----
        #pragma unroll
        for (int r = 0; r < 4; ++r) {
            float ls = 0.f;
            #pragma unroll
            for (int kb = 0; kb < 4; ++kb) {
                float pv = __expf(accS[kb][r] - m_r[r]);
                unsigned short pb = f2b(pv);
                ls += b2f(pb);
                Pl[wv][4 * g + r][kb * 16 + c] = pb;
            }
            #pragma unroll
            for (int off = 1; off < 16; off <<= 1)
                ls += __shfl_xor(ls, off, 64);
            l_r[r] += ls;
        }

        asm volatile("s_waitcnt lgkmcnt(0)" ::: "memory");
        __builtin_amdgcn_sched_barrier(0);

        // ---- PV ----
        short8 pa0 = *(const short8*)&Pl[wv][c][g * 8];
        short8 pa1 = *(const short8*)&Pl[wv][c][32 + g * 8];
        #pragma unroll
        for (int nb = 0; nb < 8; ++nb) {
            short8 vb0 = *(const short8*)&Vt[nb * 16 + c][g * 8];
            short8 vb1 = *(const short8*)&Vt[nb * 16 + c][32 + g * 8];
            accO[nb] = __builtin_amdgcn_mfma_f32_16x16x32_bf16(pa0, vb0, accO[nb], 0, 0, 0);
            accO[nb] = __builtin_amdgcn_mfma_f32_16x16x32_bf16(pa1, vb1, accO[nb], 0, 0, 0);
        }
        __syncthreads();
    }

    // ---- epilogue: unnormalized partials ----
    #pragma unroll
    for (int r = 0; r < 4; ++r) {
        int row = q0 + wv * 16 + 4 * g + r;
        if (row >= S) continue;
        size_t rowbase = (((size_t)split * S + row) * NUM_HEADS + head);
        #pragma unroll
        for (int nb = 0; nb < 8; ++nb)
            Opart[rowbase * HEAD_DIM + nb * 16 + c] = accO[nb][r];
        if (c == 0) {
            Mpart[rowbase] = m_r[r];
            Lpart[rowbase] = l_r[r];
        }
    }
}

// -------------------- combine split-K partials -> bf16 att --------------------
__global__ __launch_bounds__(256) void attn_combine(const float* __restrict__ Opart,
                                                    const float* __restrict__ Mpart,
                                                    const float* __restrict__ Lpart,
                                                    unsigned short* __restrict__ attb,
                                                    int S, int nsplit) {
    const int s = blockIdx.x;
    const int h = blockIdx.y * 2 + (threadIdx.x >> 7);
    const int d = threadIdx.x & 127;

    float mstar = -INFINITY;
    for (int i = 0; i < nsplit; ++i)
        mstar = fmaxf(mstar, Mpart[((size_t)i * S + s) * NUM_HEADS + h]);
    float L = 0.f, o = 0.f;
    for (int i = 0; i < nsplit; ++i) {
        size_t rb = ((size_t)i * S + s) * NUM_HEADS + h;
        float w = __expf(Mpart[rb] - mstar);
        L += w * Lpart[rb];
        o += w * Opart[rb * HEAD_DIM + d];
    }
    attb[(size_t)s * DIM + h * HEAD_DIM + d] = f2b(o / L);
}

// ----------------------------------- launch -----------------------------------
extern "C" void kernel_launch(void* const* d_in, const int* in_sizes, int n_in,
                              void* d_out, int out_size, void* d_ws, size_t ws_size,
                              hipStream_t stream) {
    const float* x       = (const float*)d_in[0];
    const float* fcos    = (const float*)d_in[1];
    const float* fsin    = (const float*)d_in[2];
    const float* cache_k = (const float*)d_in[3];
    const float* cache_v = (const float*)d_in[4];
    const float* Wq      = (const float*)d_in[5];
    const float* bq      = (const float*)d_in[6];
    const float* Wk      = (const float*)d_in[7];
    const float* bk      = (const float*)d_in[8];
    const float* Wv      = (const float*)d_in[9];
    const float* bv      = (const float*)d_in[10];
    const float* Wo      = (const float*)d_in[11];
    const float* bo      = (const float*)d_in[12];
    const float* gq      = (const float*)d_in[13];
    const float* gk      = (const float*)d_in[14];
    const int* gh        = (const int*)d_in[16];
    const int* gw        = (const int*)d_in[17];
    const int* cs        = (const int*)d_in[18];
    const int* ge        = (const int*)d_in[19];
    const int* le        = (const int*)d_in[20];

    const int S = in_sizes[0] / DIM;             // 1560
    const int cache_len = in_sizes[3] / DIM;     // 9360
    const int KS = ((cache_len + 63) / 64) * 64; // 9408

    const size_t SD = (size_t)S * DIM;
    float* q = (float*)d_ws;
    float* k = q + SD;
    float* v = k + SD;
    unsigned short* xb_attb = (unsigned short*)(v + SD);   // bf16 x, later bf16 att (aliased)
    unsigned short* Wb = xb_attb + SD;                     // shared bf16 weight buffer
    unsigned int* Kb = (unsigned int*)(Wb + (size_t)DIM * DIM);
    unsigned short* Vb = (unsigned short*)(Kb + (size_t)NUM_HEADS * KS * 64);  // [12][128][KS]
    float* Opart = (float*)(Vb + (size_t)NUM_HEADS * 128 * KS);

    size_t base_bytes = (size_t)((char*)Opart - (char*)d_ws);
    size_t per_split  = SD * sizeof(float) + (size_t)S * NUM_HEADS * 2 * sizeof(float);
    int nsplit = 1;
    if (ws_size > base_bytes + per_split)
        nsplit = (int)((ws_size - base_bytes) / per_split);
    if (nsplit > 4) nsplit = 4;
    if (nsplit < 1) nsplit = 1;
    float* Mpart = Opart + (size_t)nsplit * SD;
    float* Lpart = Mpart + (size_t)nsplit * S * NUM_HEADS;

    float* out = (float*)d_out;

    const long n8x = (long)SD / 8;
    const long n8w = (long)DIM * DIM / 8;
    dim3 gmm(DIM / 64, (S + 63) / 64);

    pack_mat<<<1024, 256, 0, stream>>>(x, xb_attb, n8x);
    pack_mat<<<1024, 256, 0, stream>>>(Wq, Wb, n8w);
    gemm_bf16_nt<<<gmm, 256, 0, stream>>>(xb_attb, Wb, bq, q, S, DIM, DIM);
    pack_mat<<<1024, 256, 0, stream>>>(Wk, Wb, n8w);
    gemm_bf16_nt<<<gmm, 256, 0, stream>>>(xb_attb, Wb, bk, k, S, DIM, DIM);
    pack_mat<<<1024, 256, 0, stream>>>(Wv, Wb, n8w);
    gemm_bf16_nt<<<gmm, 256, 0, stream>>>(xb_attb, Wb, bv, v, S, DIM, DIM);

    norm_rope<<<dim3(S, 2), 256, 0, stream>>>(q, k, gq, gk, fcos, fsin, gh, gw, cs);

    pack_kv<<<dim3(KS / 4, NUM_HEADS), 256, 0, stream>>>(
        k, cache_k, Kb, S, cache_len, KS, gh, gw, cs, ge, le);
    pack_vt<<<dim3(KS / 64, NUM_HEADS), 256, 0, stream>>>(
        v, cache_v, Vb, S, cache_len, KS, gh, gw, cs, ge, le);

    attn_mfma<<<dim3((S + 63) / 64, NUM_HEADS, nsplit), 256, 0, stream>>>(
        q, (const unsigned short*)Kb, Vb,
        Opart, Mpart, Lpart, S, cache_len, KS, nsplit, gh, gw, cs, ge, le);

    attn_combine<<<dim3(S, NUM_HEADS / 2), 256, 0, stream>>>(
        Opart, Mpart, Lpart, xb_attb, S, nsplit);

    pack_mat<<<1024, 256, 0, stream>>>(Wo, Wb, n8w);
    gemm_bf16_nt<<<gmm, 256, 0, stream>>>(xb_attb, Wb, bo, out, S, DIM, DIM);
}